// Round 19
// baseline (552.035 us; speedup 1.0000x reference)
//
#include <hip/hip_runtime.h>
#include <hip/hip_bf16.h>
#include <stdint.h>

#define M_TOTAL 16384
#define N_TOTAL 4096
#define K_TOTAL 4096
#define NT32 (K_TOTAL / 32)    // 128 K-steps of 32

typedef __attribute__((ext_vector_type(8))) short bf16x8;
typedef __attribute__((ext_vector_type(4))) float f32x4;

__device__ __forceinline__ void gload_lds16(const void* g, void* l) {
    __builtin_amdgcn_global_load_lds(
        (const __attribute__((address_space(1))) uint32_t*)g,
        (__attribute__((address_space(3))) uint32_t*)l, 16, 0, 0);
}

// ---------------------------------------------------------------------------
// Kernel 0: X f32 -> bf16.
// ---------------------------------------------------------------------------
__global__ __launch_bounds__(256) void k_convX(const float* __restrict__ X,
                                               __hip_bfloat16* __restrict__ Xb) {
    size_t t = (size_t)blockIdx.x * 256 + threadIdx.x;
    const float* p = X + t * 8;
    float4 a = *(const float4*)p;
    float4 b = *(const float4*)(p + 4);
    __hip_bfloat162 o[4] = {
        __float22bfloat162_rn(make_float2(a.x, a.y)),
        __float22bfloat162_rn(make_float2(a.z, a.w)),
        __float22bfloat162_rn(make_float2(b.x, b.y)),
        __float22bfloat162_rn(make_float2(b.z, b.w))};
    *(int4*)(Xb + t * 8) = *(int4*)&o[0];
}

// ---------------------------------------------------------------------------
// Kernel 1: packed int4 -> bf16 W[N][K].
// ---------------------------------------------------------------------------
__global__ __launch_bounds__(256) void k_dequant(const int* __restrict__ pw,
                                                 const float* __restrict__ sc,
                                                 __hip_bfloat16* __restrict__ W) {
    int t = blockIdx.x * 256 + threadIdx.x;
    int row = t >> 8;
    int w0 = (t & 255) << 3;
    const int* p = pw + (size_t)row * 2048 + w0;
    int4 q0 = *(const int4*)p;
    int4 q1 = *(const int4*)(p + 4);
    float s = sc[row * 128 + (w0 >> 4)];
    float ns8 = -8.0f * s;
    int w[8] = {q0.x, q0.y, q0.z, q0.w, q1.x, q1.y, q1.z, q1.w};
    __hip_bfloat162 o[8];
#pragma unroll
    for (int i = 0; i < 8; ++i) {
        float lo = fmaf((float)(w[i] & 15), s, ns8);
        float hi = fmaf((float)(w[i] >> 4), s, ns8);
        o[i] = __float22bfloat162_rn(make_float2(lo, hi));
    }
    __hip_bfloat16* dst = W + (size_t)row * 4096 + w0 * 2;
    *(int4*)dst = *(int4*)&o[0];
    *(int4*)(dst + 8) = *(int4*)&o[4];
}

// ---------------------------------------------------------------------------
// Kernel 2 (tier A): DEEP-PIPELINE ring-4. 256x256 tile, BK=32, 4 LDS bufs
// (4 x 32KB = 128KB), 8 waves (2Mx4N), per-wave 128x64, 16x16x32 MFMA,
// single-barrier phases (r18-verified).
//
// vmcnt-depth fix vs r18: tile s+2 staged ENTIRELY during step s (4 gloads,
// 2/phase) into buf (s+2)&3 -> published at end of step s+1 -> every gload
// has 3-4 phases (~1400-2100 cyc) issue-to-wait, > HBM ~900 cyc. r18's
// 2-buffer scheme forced a 1-phase distance on 2 units/step (2x ~350cyc
// stall/step). Steady VMW(4) (1 tile in flight); VMW(0) only at s=NT-2.
//
// Per step s (2 phases, 16 MFMA each, 3 BARs):
//  p1: rd A0-7,B01 (10); st A(s+2) both halves; BAR; MFMA rf0-7 x cf0-1
//  p2: rd B23 (2);       st B(s+2) both halves; BAR; MFMA rf0-7 x cf2-3
//  end: VMW(4 | 0 tail); BAR
// Races: stage(s+2) overwrites buf of tile s-2, whose last reads were
// consumed by step s-2's MFMA, 2 step-end barriers before the stage.
// Publish: tile s's 4 loads (issued step s-2) drained by VMW(4) at end of
// step s-1 (queue: [s's 4, s+1's 4] -> leaves 4 newest). Prologue stages
// tiles 0,1 (8 loads), VMW(4) publishes tile 0.
//
// Layout (BK=32, 64B rows): row-major [256][32] per region; XOR key
// ((row>>1)&3)<<3 shorts. Bank check (bytes, quarter-wave kb=0):
// start_bank(l15) = (l15*16 + ((l15>>1)&3)*4)%32 = {0,16,4,20,8,24,12,28}
// for lanes 0-7 (distinct quads, all 32 banks), lanes 8-15 repeat = free
// 2-way (m136). Same holds for kb=1,2,3 (XOR permutes within quad set).
// Source carries the involution: thread t -> row t>>2, k=(t&3)*8^((t>>3)&3)*8
// (permutes 16B chunks within one 64B row -> coalescing preserved).
// ---------------------------------------------------------------------------
__global__ __launch_bounds__(512, 2) void k_gemm19(const __hip_bfloat16* __restrict__ Xb,
                                                   const __hip_bfloat16* __restrict__ Wb,
                                                   float* __restrict__ out) {
    __shared__ __align__(16) short L[4][2][8192];  // [buf][A/B][256 rows x 32 k]

    int bid = blockIdx.x;
    int swz = (bid & 7) * 128 + (bid >> 3);        // XCD-bijective (1024%8==0)
    int bn = swz & 15, bm = swz >> 4;
    int m0 = bm * 256, n0 = bn * 256;
    int t = threadIdx.x, lane = t & 63, wv = t >> 6;
    int wm = wv >> 2, wn = wv & 3;

    // staging source: thread t -> row t>>2 (0..127; +128 for g=1),
    // k = (t&3)*8 ^ ((t>>3)&3)*8  (pre-applied involution)
    int srow = t >> 2;
    int sko = ((t & 3) * 8) ^ (((t >> 3) & 3) * 8);
    const __hip_bfloat16* gA = Xb + (size_t)(m0 + srow) * K_TOTAL + sko;
    const __hip_bfloat16* gB = Wb + (size_t)(n0 + srow) * K_TOTAL + sko;

    auto stA = [&](int b, int g, int T) {
        gload_lds16(gA + (size_t)(g * 128) * K_TOTAL + T * 32, &L[b][0][g * 4096 + t * 8]);
    };
    auto stB = [&](int b, int g, int T) {
        gload_lds16(gB + (size_t)(g * 128) * K_TOTAL + T * 32, &L[b][1][g * 4096 + t * 8]);
    };

    // frag-read lane constants: key = ((row>>1)&3)<<3 with row=base16+l15
    const int l15 = lane & 15;
    const int kx = ((lane >> 4) * 8) ^ (((l15 >> 1) & 3) << 3);
    const int lro = l15 * 32 + kx;

    f32x4 acc[8][4];
#pragma unroll
    for (int f = 0; f < 8; ++f)
#pragma unroll
        for (int j = 0; j < 4; ++j) acc[f][j] = (f32x4)(0.0f);

    bf16x8 Af[8], Bq01[2], Bq23[2];

#define BAR __builtin_amdgcn_s_barrier()
#define PRI(x) __builtin_amdgcn_s_setprio(x)
#define VMW(n) { asm volatile("s_waitcnt vmcnt(" #n ")" ::: "memory"); \
                 __builtin_amdgcn_sched_barrier(0); }
#define MMH(cb, Bv) { _Pragma("unroll") for (int rf = 0; rf < 8; ++rf) \
    _Pragma("unroll") for (int cf = 0; cf < 2; ++cf) \
        acc[rf][(cb) + cf] = __builtin_amdgcn_mfma_f32_16x16x32_bf16( \
            Af[rf], Bv[cf], acc[rf][(cb) + cf], 0, 0, 0); }

#define STEP(S, CUR, N2)                                                       \
    {                                                                          \
        const int s_ = (S);                                                    \
        const bool g2 = (s_ + 2 < NT32);                                       \
        const bool g1 = (s_ + 1 < NT32);                                       \
        const short* LA = &L[CUR][0][0];                                       \
        const short* LB = &L[CUR][1][0];                                       \
        /* p1 */                                                               \
        _Pragma("unroll")                                                      \
        for (int rf = 0; rf < 8; ++rf)                                         \
            Af[rf] = *(const bf16x8*)&LA[wm * 4096 + rf * 512 + lro];          \
        Bq01[0] = *(const bf16x8*)&LB[wn * 2048 + lro];                        \
        Bq01[1] = *(const bf16x8*)&LB[wn * 2048 + 512 + lro];                  \
        if (g2) { stA(N2, 0, s_ + 2); stA(N2, 1, s_ + 2); }                    \
        BAR; PRI(1); MMH(0, Bq01) PRI(0);                                      \
        /* p2 */                                                               \
        Bq23[0] = *(const bf16x8*)&LB[wn * 2048 + 1024 + lro];                 \
        Bq23[1] = *(const bf16x8*)&LB[wn * 2048 + 1536 + lro];                 \
        if (g2) { stB(N2, 0, s_ + 2); stB(N2, 1, s_ + 2); }                    \
        BAR; PRI(1); MMH(2, Bq23) PRI(0);                                      \
        /* step end: publish tile s+1 */                                       \
        if (g2)      { VMW(4) BAR; }                                           \
        else if (g1) { VMW(0) BAR; }                                           \
    }

    // ---- prologue: stage tiles 0,1; publish tile 0 ----
    stA(0, 0, 0); stA(0, 1, 0); stB(0, 0, 0); stB(0, 1, 0);
    stA(1, 0, 1); stA(1, 1, 1); stB(1, 0, 1); stB(1, 1, 1);
    VMW(4);
    BAR;

    for (int i = 0; i < NT32 / 4; ++i) {
        STEP(4 * i,     0, 2)
        STEP(4 * i + 1, 1, 3)
        STEP(4 * i + 2, 2, 0)
        STEP(4 * i + 3, 3, 1)
    }
#undef STEP
#undef MMH
#undef BAR
#undef PRI
#undef VMW

    // ---- epilogue: C/D layout col=lane&15, row=(lane>>4)*4+reg ----
    int col0 = n0 + wn * 64 + l15;
    int row0 = m0 + wm * 128 + (lane >> 4) * 4;
#pragma unroll
    for (int f = 0; f < 8; ++f)
#pragma unroll
        for (int j = 0; j < 4; ++j) {
            f32x4 v = acc[f][j];
            int r = row0 + f * 16;
            int c = col0 + j * 16;
#pragma unroll
            for (int q = 0; q < 4; ++q)
                out[(size_t)(r + q) * N_TOTAL + c] = v[q];
        }
}

// ---------------------------------------------------------------------------
// Tier B: m97-structure GEMM, A reg-staged from f32 X (round-5 verified).
// ---------------------------------------------------------------------------
__global__ __launch_bounds__(256) void k_gemm2b(const float* __restrict__ X,
                                                const __hip_bfloat16* __restrict__ Wb,
                                                float* __restrict__ out) {
    __shared__ __align__(16) short As[128 * 32];
    __shared__ __align__(16) short Bs[128 * 32];
    int bid = blockIdx.x;
    int swz = (bid & 7) * 512 + (bid >> 3);
    int bn = swz & 31, bm = swz >> 5;
    int m0 = bm * 128, n0 = bn * 128;
    int t = threadIdx.x, lane = t & 63, wv = t >> 6;
    int wr = wv >> 1, wc = wv & 1;
    f32x4 acc[4][4];
#pragma unroll
    for (int i = 0; i < 4; ++i)
#pragma unroll
        for (int j = 0; j < 4; ++j) acc[i][j] = (f32x4)(0.0f);
    int arow = t >> 2, acol = (t & 3) * 8;
    const float* Agf0 = X + (size_t)(m0 + arow) * K_TOTAL + acol;
    const float* Agf1 = Agf0 + (size_t)64 * K_TOTAL;
    const __hip_bfloat16* Bg0 = Wb + (size_t)(n0 + arow) * K_TOTAL + acol;
    const __hip_bfloat16* Bg1 = Bg0 + (size_t)64 * K_TOTAL;
    float4 xa0 = *(const float4*)(Agf0), xa1 = *(const float4*)(Agf0 + 4);
    float4 xb0 = *(const float4*)(Agf1), xb1 = *(const float4*)(Agf1 + 4);
    for (int kt = 0; kt < NT32; ++kt) {
        if (kt) __syncthreads();
        __hip_bfloat162 oa[4] = {
            __float22bfloat162_rn(make_float2(xa0.x, xa0.y)),
            __float22bfloat162_rn(make_float2(xa0.z, xa0.w)),
            __float22bfloat162_rn(make_float2(xa1.x, xa1.y)),
            __float22bfloat162_rn(make_float2(xa1.z, xa1.w))};
        __hip_bfloat162 ob[4] = {
            __float22bfloat162_rn(make_float2(xb0.x, xb0.y)),
            __float22bfloat162_rn(make_float2(xb0.z, xb0.w)),
            __float22bfloat162_rn(make_float2(xb1.x, xb1.y)),
            __float22bfloat162_rn(make_float2(xb1.z, xb1.w))};
        *(int4*)&As[t * 8] = *(int4*)&oa[0];
        *(int4*)&As[2048 + t * 8] = *(int4*)&ob[0];
        gload_lds16(Bg0 + kt * 32, &Bs[t * 8]);
        gload_lds16(Bg1 + kt * 32, &Bs[2048 + t * 8]);
        __syncthreads();
        if (kt < NT32 - 1) {
            int ko = (kt + 1) * 32;
            xa0 = *(const float4*)(Agf0 + ko);
            xa1 = *(const float4*)(Agf0 + ko + 4);
            xb0 = *(const float4*)(Agf1 + ko);
            xb1 = *(const float4*)(Agf1 + ko + 4);
        }
        bf16x8 a[4], b[4];
        int ro = (lane & 15) * 32 + (lane >> 4) * 8;
#pragma unroll
        for (int i = 0; i < 4; ++i)
            a[i] = *(const bf16x8*)&As[(wr * 64 + i * 16) * 32 + ro];
#pragma unroll
        for (int j = 0; j < 4; ++j)
            b[j] = *(const bf16x8*)&Bs[(wc * 64 + j * 16) * 32 + ro];
#pragma unroll
        for (int i = 0; i < 4; ++i)
#pragma unroll
            for (int j = 0; j < 4; ++j)
                acc[i][j] = __builtin_amdgcn_mfma_f32_16x16x32_bf16(a[i], b[j], acc[i][j], 0, 0, 0);
    }
    int col0 = n0 + wc * 64 + (lane & 15);
    int row0 = m0 + wr * 64 + (lane >> 4) * 4;
#pragma unroll
    for (int i = 0; i < 4; ++i)
#pragma unroll
        for (int j = 0; j < 4; ++j) {
            f32x4 v = acc[i][j];
            int r = row0 + i * 16, c = col0 + j * 16;
#pragma unroll
            for (int q = 0; q < 4; ++q)
                out[(size_t)(r + q) * N_TOTAL + c] = v[q];
        }
}

extern "C" void kernel_launch(void* const* d_in, const int* in_sizes, int n_in,
                              void* d_out, int out_size, void* d_ws, size_t ws_size,
                              hipStream_t stream) {
    const float* X = (const float*)d_in[0];
    const int* PW = (const int*)d_in[1];
    const float* SC = (const float*)d_in[2];
    float* OUT = (float*)d_out;

    const size_t needW = (size_t)N_TOTAL * K_TOTAL * 2;            // 33.5 MB
    const size_t needX = needW + (size_t)M_TOTAL * K_TOTAL * 2;    // +134 MB

    if (ws_size >= needX) {
        __hip_bfloat16* Wb = (__hip_bfloat16*)d_ws;
        __hip_bfloat16* Xb = (__hip_bfloat16*)((char*)d_ws + needW);
        k_convX<<<dim3(32768), dim3(256), 0, stream>>>(X, Xb);
        k_dequant<<<dim3(4096), dim3(256), 0, stream>>>(PW, SC, Wb);
        k_gemm19<<<dim3((M_TOTAL / 256) * (N_TOTAL / 256)), dim3(512), 0, stream>>>(Xb, Wb, OUT);
    } else if (ws_size >= needW) {
        __hip_bfloat16* Wb = (__hip_bfloat16*)d_ws;
        k_dequant<<<dim3(4096), dim3(256), 0, stream>>>(PW, SC, Wb);
        k_gemm2b<<<dim3((M_TOTAL / 128) * (N_TOTAL / 128)), dim3(256), 0, stream>>>(X, Wb, OUT);
    }
}